// Round 6
// baseline (192.717 us; speedup 1.0000x reference)
//
#include <hip/hip_runtime.h>

// mp: [1, 21, 16, 256, 256] fp32
#define CC   21
#define DD   16
#define HH   256
#define WW   256
#define HWP  (HH * WW)      // 65536
#define DHW  (DD * HWP)     // 1048576

typedef float f4a __attribute__((ext_vector_type(4), aligned(16)));
__device__ __forceinline__ f4a f4add(f4a a, f4a b) { return a + b; }

// ---------------------------------------------------------------------------
// K1: D-blur (registers) + H-blur (LDS), H-RING version.
// Block = (wt, hseg of 32 h-rows, ch). LDS = 16-row ring per d-plane:
// A[(plane*16 + (idx&15))*36 + x4*4], idx = staged-row index within segment
// (staged h = hseg0 + idx - 2, clamped). Step 0 stages idx 0..11 (bitwise
// the verified 12-row tile stage); steps 1..3 stage only the 8 NEW rows
// (idx 8k+4..8k+11) -> H-halo redundancy 1.5x -> 1.125x (reads 132->99 MB),
// and the per-block load pulse is amortized over 4 tiles.
// Ring safety: stage k overwrites phys slots holding idx <= 8k-5; H-pass k-1
// reads idx >= 8k-8 -> barrier after H-pass before next stage (kept), plus
// barrier after stage before H-pass. Same 2-barriers-per-8-rows as verified.
// All sums, clamps, and store addresses bit-identical to the verified kernel.
// ---------------------------------------------------------------------------
#define AROW 36
#define PYR  16                        // ring depth (pow2)
#define A_SZ (DD * PYR * AROW)         // 16*16*36 = 9216 floats = 36864 B -> 4/CU

#define NSEG 8                         // 8 h-segments x 32 rows
#define NB1  (8 * NSEG * CC)           // wt x hseg x ch = 1344 blocks
#define CHK1 (NB1 / 8)                 // 168 per XCD (bijective)

// verified round-5 chains, re-indexed into P[16]:
// s=0: l[m] = P[clamp(m-2)]   s=1: l[m] = P[clamp(6+m)]
__device__ __forceinline__ void stage_col(const float* __restrict__ src, int h0seg,
                                          int idx, int x4, float* __restrict__ A) {
    const int h = min(HH - 1, max(0, h0seg + idx - 2));
    const float* colp = src + (size_t)h * WW + x4 * 4;
    const int phys = idx & 15;

    f4a P[16];
#pragma unroll
    for (int d = 0; d < 16; ++d) P[d] = *(const f4a*)(colp + (size_t)d * HWP);

    constexpr int M0[12] = {0, 0, 0, 1, 2, 3, 4, 5, 6, 7, 8, 9};
    constexpr int M1[12] = {6, 7, 8, 9, 10, 11, 12, 13, 14, 15, 15, 15};

    {   // s = 0: planes 0..7
        f4a sum = f4add(f4add(f4add(P[M0[0]], P[M0[1]]),
                              f4add(P[M0[2]], P[M0[3]])), P[M0[4]]);
#pragma unroll
        for (int i = 0; i < 8; ++i) {
            *(f4a*)(&A[(i * PYR + phys) * AROW + x4 * 4]) = sum;
            if (i < 7) sum = sum - P[M0[i]] + P[M0[i + 5]];
        }
    }
    {   // s = 1: planes 8..15
        f4a sum = f4add(f4add(f4add(P[M1[0]], P[M1[1]]),
                              f4add(P[M1[2]], P[M1[3]])), P[M1[4]]);
#pragma unroll
        for (int i = 0; i < 8; ++i) {
            *(f4a*)(&A[((8 + i) * PYR + phys) * AROW + x4 * 4]) = sum;
            if (i < 7) sum = sum - P[M1[i]] + P[M1[i + 5]];
        }
    }
}

__global__ __launch_bounds__(256, 4) void dh_blur_kernel(const float* __restrict__ mp,
                                                         float* __restrict__ out) {
    __shared__ float A[A_SZ];
    const int tid = threadIdx.x;

    // bijective XCD-chunked order
    const int bid  = blockIdx.x;
    const int t    = (bid & 7) * CHK1 + (bid >> 3);
    const int wt   = t & 7;
    const int hseg = (t >> 3) & 7;
    const int ch   = t >> 6;
    const int w0   = wt * 32;
    const int h0seg = hseg * 32;
    const float* __restrict__ src = mp + (size_t)ch * DHW + w0;

    // ---- step 0 stage: idx 0..11 (bitwise the verified 12-row tile) ----
    if (tid < 96) stage_col(src, h0seg, tid >> 3, tid & 7, A);
    __syncthreads();

#pragma unroll
    for (int k = 0; k < 4; ++k) {
        // ---- H pass for tile k: output rows h0seg + 8k + y, verbatim math ----
#pragma unroll
        for (int it = 0; it < 4; ++it) {
            const int tt   = tid + it * 256;
            const int xx4  = tt & 7;
            const int y    = (tt >> 3) & 7;
            const int dout = tt >> 6;
            const int idx0 = 8 * k + y;

            f4a a = *(const f4a*)(&A[(dout * PYR + (idx0 & 15)) * AROW + xx4 * 4]);
#pragma unroll
            for (int kk = 1; kk < 5; ++kk)
                a = f4add(a, *(const f4a*)(&A[(dout * PYR + ((idx0 + kk) & 15)) * AROW + xx4 * 4]));

            *(f4a*)(out + (size_t)ch * DHW + (size_t)dout * HWP
                    + (size_t)(h0seg + 8 * k + y) * WW + w0 + xx4 * 4) = a;
        }

        if (k < 3) {
            __syncthreads();   // ring rows idx 8k.. still read above; drain before overwrite
            // ---- stage 8 new rows: idx 8(k+1)+4 .. 8(k+1)+11 ----
            if (tid < 64) stage_col(src, h0seg, 8 * (k + 1) + 4 + (tid >> 3), tid & 7, A);
            __syncthreads();
        }
    }
}

// ---------------------------------------------------------------------------
// K2: W-blur + weighted-median, verbatim verified round-1 kernel.
// Block = one (d,h) row, all 21 channels staged in LDS (22.2 KB -> 7/CU).
// In-place safe: a row is read and overwritten only by its own block.
// ---------------------------------------------------------------------------
#define ROWP 264   // 2 pad + 2 lo-edge + 256 data + 2 hi-edge + 2 pad

__global__ __launch_bounds__(256) void wmedian_kernel(float* __restrict__ y4) {
    __shared__ float R[CC * ROWP];

    const int h = blockIdx.x;
    const int d = blockIdx.y;
    const int tid = threadIdx.x;
    float* __restrict__ base = y4 + (size_t)d * HWP + (size_t)h * WW;

    for (int idx = tid; idx < CC * 64; idx += 256) {
        const int c  = idx >> 6;
        const int w4 = idx & 63;
        *(f4a*)(&R[c * ROWP + 4 + w4 * 4]) = *(const f4a*)(base + (size_t)c * DHW + w4 * 4);
    }
    if (tid < CC) {
        const float v0 = base[(size_t)tid * DHW];
        const float vL = base[(size_t)tid * DHW + (WW - 1)];
        R[tid * ROWP + 2]   = v0;
        R[tid * ROWP + 3]   = v0;
        R[tid * ROWP + 260] = vL;
        R[tid * ROWP + 261] = vL;
    }
    __syncthreads();

    const int w = tid;   // 0..255
    float v[CC];
    float tot = 0.f;
#pragma unroll
    for (int c = 0; c < CC; ++c) {
        const float* r = &R[c * ROWP + 2 + w];           // r[0] = value at w-2
        v[c] = ((((r[0] + r[1]) + r[2]) + r[3]) + r[4]); // verified W order
        tot += v[c];
    }
    const float inv = 1.0f / tot;

    float s = 0.f, sv0 = 0.f, sv1 = 0.f;
    int m0 = 0, m1 = 0;
#pragma unroll
    for (int c = 0; c < CC; ++c) {
        const float yn = v[c] * inv;
        const float sn = s + yn;
        if (c == 0) { sv0 = yn; sv1 = yn; }                           // defaults
        if (v[c] > 0.f && sn < 0.5f) { m0 = c; sv0 = yn; }            // last qualifying
        if (m1 == 0 && c > 0 && sn > 0.5f) { m1 = c; sv1 = yn; }      // first qualifying
        s = sn;
    }

#pragma unroll
    for (int c = 0; c < CC; ++c) {
        base[(size_t)c * DHW + w] = (c == m0) ? sv0 : ((c == m1) ? sv1 : 0.f);
    }
}

extern "C" void kernel_launch(void* const* d_in, const int* in_sizes, int n_in,
                              void* d_out, int out_size, void* d_ws, size_t ws_size,
                              hipStream_t stream) {
    const float* mp = (const float*)d_in[0];
    float* out = (float*)d_out;

    dh_blur_kernel<<<NB1, 256, 0, stream>>>(mp, out);       // 1344 blocks, 4 tiles each
    wmedian_kernel<<<dim3(HH, DD), 256, 0, stream>>>(out);  // 4096 blocks
}

// Round 7
// 185.422 us; speedup vs baseline: 1.0393x; 1.0393x over previous
//
#include <hip/hip_runtime.h>

// mp: [1, 21, 16, 256, 256] fp32
#define CC   21
#define DD   16
#define HH   256
#define WW   256
#define HWP  (HH * WW)      // 65536
#define DHW  (DD * HWP)     // 1048576

typedef float f4a __attribute__((ext_vector_type(4), aligned(16)));
__device__ __forceinline__ f4a f4add(f4a a, f4a b) { return a + b; }

// global -> LDS direct (async DMA, no VGPR round-trip). Per-lane GLOBAL addr,
// wave-uniform LDS base + lane*16B. Size must be a literal 16.
#define GLDS16(gp, lp)                                                        \
    __builtin_amdgcn_global_load_lds(                                         \
        (const __attribute__((address_space(1))) void*)(gp),                  \
        (__attribute__((address_space(3))) void*)(lp), 16, 0, 0)

// ---------------------------------------------------------------------------
// K1: raw-stage via global_load_lds + in-place D-chain + H-pass.
// LDS raw[d][py][32f] packed (stride 32): linear words n = d*384+py*32+x4*4,
// 6144 floats = 24.6 KB. Stage = 24 wave-instructions (1 KB each), 6 PER WAVE
// (all 4 waves stage!), issued back-to-back with no dependent use -> global
// latency exposed once per block at the barrier, not per-chain.
// Phase A (tid<96): column task (py,x4) reads its 16 planes from LDS into
// registers (verified order), runs BOTH verified sliding chains, writes the
// 16 D-blurred planes back to the SAME slots (in-place safe: reads precede
// writes within the only thread touching that column).
// Phase B: verified H-pass (stride 32). All LDS patterns are phase-minimal:
// each wave's 64 lanes put exactly 8 words on each of the 32 banks.
// Arithmetic / clamps / store addresses bit-identical to the round-5 kernel.
// ---------------------------------------------------------------------------
#define A_SZ (DD * PYN_ * 32)
#define PYN_ 12

#define NB1  (8 * 32 * CC)       // 5376 blocks
#define CHK1 (NB1 / 8)           // 672 per XCD (bijective)

__global__ __launch_bounds__(256, 5) void dh_blur_kernel(const float* __restrict__ mp,
                                                         float* __restrict__ out) {
    __shared__ float A[DD * PYN_ * 32];   // 6144 floats, packed
    const int tid = threadIdx.x;

    // bijective XCD-chunked order (R5)
    const int bid = blockIdx.x;
    const int t   = (bid & 7) * CHK1 + (bid >> 3);
    const int yb  = t & 31;
    const int wt  = (t >> 5) & 7;
    const int ch  = t >> 8;
    const int w0  = wt * 32;
    const int h0  = yb * 8;
    const float* __restrict__ src = mp + (size_t)ch * DHW + w0;

    // ---- stage: 24 x global_load_lds_dwordx4, 6 per wave, no register RT ----
    {
        const int wv   = tid >> 6;         // wave 0..3
        const int lane = tid & 63;
#pragma unroll
        for (int j = 0; j < 6; ++j) {
            const int inst = wv * 6 + j;               // 0..23
            const int idx4 = inst * 64 + lane;         // vec4 index 0..1535
            const int d    = idx4 / 96;                // plane 0..15
            const int r    = idx4 - d * 96;
            const int py   = r >> 3;                   // 0..11
            const int x4   = r & 7;                    // 0..7
            const int h    = min(HH - 1, max(0, h0 + py - 2));
            const float* gp = src + (size_t)d * HWP + (size_t)h * WW + x4 * 4;
            GLDS16(gp, &A[inst * 256]);                // wave-uniform LDS base
        }
    }
    __syncthreads();   // drains vmcnt -> raw tile resident in LDS

    // ---- phase A: in-place D-blur per column (verified chains) ----
    if (tid < 96) {
        const int py = tid >> 3;             // 0..11
        const int x4 = tid & 7;              // quad 0..7
        float* colA = &A[py * 32 + x4 * 4];  // + d*384

        f4a P[16];
#pragma unroll
        for (int d = 0; d < 16; ++d) P[d] = *(const f4a*)(colA + d * 384);

        constexpr int M0[12] = {0, 0, 0, 1, 2, 3, 4, 5, 6, 7, 8, 9};
        constexpr int M1[12] = {6, 7, 8, 9, 10, 11, 12, 13, 14, 15, 15, 15};

        {   // s = 0: planes 0..7
            f4a sum = f4add(f4add(f4add(P[M0[0]], P[M0[1]]),
                                  f4add(P[M0[2]], P[M0[3]])), P[M0[4]]);
#pragma unroll
            for (int i = 0; i < 8; ++i) {
                *(f4a*)(colA + i * 384) = sum;
                if (i < 7) sum = sum - P[M0[i]] + P[M0[i + 5]];
            }
        }
        {   // s = 1: planes 8..15
            f4a sum = f4add(f4add(f4add(P[M1[0]], P[M1[1]]),
                                  f4add(P[M1[2]], P[M1[3]])), P[M1[4]]);
#pragma unroll
            for (int i = 0; i < 8; ++i) {
                *(f4a*)(colA + (8 + i) * 384) = sum;
                if (i < 7) sum = sum - P[M1[i]] + P[M1[i + 5]];
            }
        }
    }
    __syncthreads();

    // ---- phase B: verified H-pass (stride 32) + stores ----
#pragma unroll
    for (int it = 0; it < 4; ++it) {
        const int tt   = tid + it * 256;
        const int xx4  = tt & 7;
        const int y    = (tt >> 3) & 7;
        const int dout = tt >> 6;

        const float* b = &A[dout * 384 + y * 32 + xx4 * 4];
        f4a a = *(const f4a*)b;
#pragma unroll
        for (int k = 1; k < 5; ++k) a = f4add(a, *(const f4a*)(b + k * 32));

        *(f4a*)(out + (size_t)ch * DHW + (size_t)dout * HWP
                + (size_t)(h0 + y) * WW + w0 + xx4 * 4) = a;
    }
}

// ---------------------------------------------------------------------------
// K2: W-blur + weighted-median, verbatim verified round-1 kernel (6.5 TB/s).
// ---------------------------------------------------------------------------
#define ROWP 264   // 2 pad + 2 lo-edge + 256 data + 2 hi-edge + 2 pad

__global__ __launch_bounds__(256) void wmedian_kernel(float* __restrict__ y4) {
    __shared__ float R[CC * ROWP];

    const int h = blockIdx.x;
    const int d = blockIdx.y;
    const int tid = threadIdx.x;
    float* __restrict__ base = y4 + (size_t)d * HWP + (size_t)h * WW;

    for (int idx = tid; idx < CC * 64; idx += 256) {
        const int c  = idx >> 6;
        const int w4 = idx & 63;
        *(f4a*)(&R[c * ROWP + 4 + w4 * 4]) = *(const f4a*)(base + (size_t)c * DHW + w4 * 4);
    }
    if (tid < CC) {
        const float v0 = base[(size_t)tid * DHW];
        const float vL = base[(size_t)tid * DHW + (WW - 1)];
        R[tid * ROWP + 2]   = v0;
        R[tid * ROWP + 3]   = v0;
        R[tid * ROWP + 260] = vL;
        R[tid * ROWP + 261] = vL;
    }
    __syncthreads();

    const int w = tid;   // 0..255
    float v[CC];
    float tot = 0.f;
#pragma unroll
    for (int c = 0; c < CC; ++c) {
        const float* r = &R[c * ROWP + 2 + w];           // r[0] = value at w-2
        v[c] = ((((r[0] + r[1]) + r[2]) + r[3]) + r[4]); // verified W order
        tot += v[c];
    }
    const float inv = 1.0f / tot;

    float s = 0.f, sv0 = 0.f, sv1 = 0.f;
    int m0 = 0, m1 = 0;
#pragma unroll
    for (int c = 0; c < CC; ++c) {
        const float yn = v[c] * inv;
        const float sn = s + yn;
        if (c == 0) { sv0 = yn; sv1 = yn; }                           // defaults
        if (v[c] > 0.f && sn < 0.5f) { m0 = c; sv0 = yn; }            // last qualifying
        if (m1 == 0 && c > 0 && sn > 0.5f) { m1 = c; sv1 = yn; }      // first qualifying
        s = sn;
    }

#pragma unroll
    for (int c = 0; c < CC; ++c) {
        base[(size_t)c * DHW + w] = (c == m0) ? sv0 : ((c == m1) ? sv1 : 0.f);
    }
}

extern "C" void kernel_launch(void* const* d_in, const int* in_sizes, int n_in,
                              void* d_out, int out_size, void* d_ws, size_t ws_size,
                              hipStream_t stream) {
    const float* mp = (const float*)d_in[0];
    float* out = (float*)d_out;

    dh_blur_kernel<<<NB1, 256, 0, stream>>>(mp, out);       // 5376 blocks, XCD-chunked
    wmedian_kernel<<<dim3(HH, DD), 256, 0, stream>>>(out);  // 4096 blocks
}